// Round 5
// baseline (1176.228 us; speedup 1.0000x reference)
//
#include <hip/hip_runtime.h>

#define N_USER 50000
#define N_ITEM 100000
#define N_NODES 150000
#define EMB 64
#define NNZ 2400000
#define BATCH 4096
#define NSAMP (3 * BATCH)                     // 12288 sampled rows
#define SCAN_BLOCKS ((N_NODES + 255) / 256)   // 586

// ---------------- init: ego = concat(user_emb, item_emb), float4 copy ----------------
__global__ __launch_bounds__(256) void init_ego(const float4* __restrict__ ue,
                                                const float4* __restrict__ ie,
                                                float4* __restrict__ ego) {
    int i = blockIdx.x * 256 + threadIdx.x;
    if (i >= N_NODES * EMB / 4) return;
    const int NU4 = N_USER * EMB / 4;
    ego[i] = (i < NU4) ? ue[i] : ie[i - NU4];
}

// ---------------- CSR build ----------------
__global__ __launch_bounds__(256) void hist(const int* __restrict__ rows, int* __restrict__ cnt) {
    int e = blockIdx.x * 256 + threadIdx.x;
    if (e < NNZ) atomicAdd(&cnt[rows[e]], 1);
}

__global__ __launch_bounds__(256) void scan_k1(const int* __restrict__ cnt,
                                               int* __restrict__ row_start,
                                               int* __restrict__ partials) {
    __shared__ int s[256];
    int t = threadIdx.x, i = blockIdx.x * 256 + t;
    int v = (i < N_NODES) ? cnt[i] : 0;
    s[t] = v;
    for (int off = 1; off < 256; off <<= 1) {
        __syncthreads();
        int add = (t >= off) ? s[t - off] : 0;
        __syncthreads();
        s[t] += add;
    }
    if (i < N_NODES) row_start[i] = s[t] - v;
    if (t == 255) partials[blockIdx.x] = s[255];
}

__global__ __launch_bounds__(1024) void scan_k2(int* __restrict__ partials, int nb) {
    __shared__ int s[1024];
    int t = threadIdx.x;
    int v = (t < nb) ? partials[t] : 0;
    s[t] = v;
    for (int off = 1; off < 1024; off <<= 1) {
        __syncthreads();
        int add = (t >= off) ? s[t - off] : 0;
        __syncthreads();
        s[t] += add;
    }
    if (t < nb) partials[t] = s[t] - v;
}

__global__ __launch_bounds__(256) void scan_k3(int* __restrict__ row_start,
                                               const int* __restrict__ partials,
                                               int* __restrict__ cursor) {
    int i = blockIdx.x * 256 + threadIdx.x;
    if (i < N_NODES) {
        int v = row_start[i] + partials[blockIdx.x];
        row_start[i] = v;
        cursor[i] = v;
    }
    if (i == 0) row_start[N_NODES] = NNZ;
}

__global__ __launch_bounds__(256) void scatter_edges(const int* __restrict__ rows,
                                                     const int* __restrict__ cols,
                                                     const float* __restrict__ vals,
                                                     int* __restrict__ cursor,
                                                     int2* __restrict__ ecv) {
    int e = blockIdx.x * 256 + threadIdx.x;
    if (e >= NNZ) return;
    int pos = atomicAdd(&cursor[rows[e]], 1);
    ecv[pos] = make_int2(cols[e], __float_as_int(vals[e]));
}

// ======== core per-node compute: fixed-unroll CSR gather-reduce + dense transform ========
__device__ __forceinline__ void node_compute(int node,
                                             const int* __restrict__ row_start,
                                             const int2* __restrict__ ecv,
                                             const float* __restrict__ ego_in,
                                             const float* __restrict__ lwgc,
                                             const float* __restrict__ lwbi,
                                             const float* __restrict__ bgc,
                                             const float* __restrict__ bbi,
                                             int layer, int lane,
                                             float& x_out, float& inv_out) {
    const int j = lane >> 4;            // edge slot within quad (0..3)
    const int g = (lane & 15) << 2;     // dim offset (float4 group)
    const int s0 = row_start[node];
    const int s1 = row_start[node + 1];

    // hoisted: self-row + biases overlap with the gather loop
    const size_t base = (size_t)node * EMB;
    const float4 e4 = *(const float4*)(ego_in + base + ((lane & 15) << 2));
    const float bias = bgc[layer * 64 + lane] + bbi[layer * 64 + lane];

    float4 acc0 = make_float4(0.f, 0.f, 0.f, 0.f);
    float4 acc1 = make_float4(0.f, 0.f, 0.f, 0.f);
    for (int e0 = s0; e0 < s1; e0 += 64) {
        const int cnt = min(64, s1 - e0);
        int2 m = make_int2(0, 0);                      // zero-fill: pad slots are no-ops
        if (lane < cnt) m = ecv[e0 + lane];
        // FIXED 8-iteration body: fully unrolled, 16 independent float4 loads in flight
#pragma unroll
        for (int jj = 0; jj < 64; jj += 8) {
            int   i0 = jj + j;
            int   c0 = __shfl(m.x, i0);
            float v0 = __int_as_float(__shfl(m.y, i0));
            const float4 x0 = *(const float4*)(ego_in + (size_t)c0 * EMB + g);
            int   i1 = jj + 4 + j;
            int   c1 = __shfl(m.x, i1);
            float v1 = __int_as_float(__shfl(m.y, i1));
            const float4 x1 = *(const float4*)(ego_in + (size_t)c1 * EMB + g);
            acc0.x = fmaf(v0, x0.x, acc0.x); acc0.y = fmaf(v0, x0.y, acc0.y);
            acc0.z = fmaf(v0, x0.z, acc0.z); acc0.w = fmaf(v0, x0.w, acc0.w);
            acc1.x = fmaf(v1, x1.x, acc1.x); acc1.y = fmaf(v1, x1.y, acc1.y);
            acc1.z = fmaf(v1, x1.z, acc1.z); acc1.w = fmaf(v1, x1.w, acc1.w);
        }
    }
    float av[4] = { acc0.x + acc1.x, acc0.y + acc1.y, acc0.z + acc1.z, acc0.w + acc1.w };
#pragma unroll
    for (int c = 0; c < 4; ++c) {
        av[c] += __shfl_xor(av[c], 16);
        av[c] += __shfl_xor(av[c], 32);
    }
    // every lane holds side[node][4*(lane&15)+c] in av[c]

    float cv[4] = { e4.x * av[0], e4.y * av[1], e4.z * av[2], e4.w * av[3] };

    float acc = bias;
#pragma unroll
    for (int jq = 0; jq < 16; ++jq) {
#pragma unroll
        for (int c = 0; c < 4; ++c) {
            const int jd = jq * 4 + c;
            float bj = __shfl(av[c], jq);
            float dj = __shfl(cv[c], jq);
            acc = fmaf(bj, lwgc[jd * 64 + lane], acc);
            acc = fmaf(dj, lwbi[jd * 64 + lane], acc);
        }
    }
    float x = (acc >= 0.f) ? acc : 0.2f * acc;         // leaky_relu 0.2

    float s = x * x;                                   // wave-64 L2 norm
#pragma unroll
    for (int off = 32; off > 0; off >>= 1) s += __shfl_xor(s, off);
    x_out = x;
    inv_out = 1.0f / fmaxf(sqrtf(s), 1e-12f);
}

// ---- full-layer fused kernel: 1024 threads = 16 nodes/block (100% occupancy: 2 blk/CU) ----
__global__ __launch_bounds__(1024) void spmm_dense(const int* __restrict__ row_start,
                                                   const int2* __restrict__ ecv,
                                                   const float* __restrict__ ego_in,
                                                   float* __restrict__ ego_out,
                                                   const float* __restrict__ Wgc,
                                                   const float* __restrict__ bgc,
                                                   const float* __restrict__ Wbi,
                                                   const float* __restrict__ bbi,
                                                   float* __restrict__ inv_norm,
                                                   int layer) {
    __shared__ float lwgc[64 * 64];
    __shared__ float lwbi[64 * 64];
    const int t = threadIdx.x;
    const int lane = t & 63;
    const int node = blockIdx.x * 16 + (t >> 6);       // grid = 9375 → exactly 150000 nodes

    const float* Wg = Wgc + layer * EMB * EMB;
    const float* Wb = Wbi + layer * EMB * EMB;
    for (int idx = t; idx < 64 * 64; idx += 1024) {
        lwgc[idx] = Wg[idx];
        lwbi[idx] = Wb[idx];
    }
    __syncthreads();

    float x, inv;
    node_compute(node, row_start, ecv, ego_in, lwgc, lwbi, bgc, bbi, layer, lane, x, inv);
    ego_out[(size_t)node * EMB + lane] = x;
    if (lane == 0) inv_norm[node] = inv;
}

// ---- last-layer kernel: only the 12288 sampled rows, writes normalized slice into out ----
__global__ __launch_bounds__(1024) void spmm_dense_sampled(const int* __restrict__ row_start,
                                                           const int2* __restrict__ ecv,
                                                           const float* __restrict__ ego_in,
                                                           const int* __restrict__ users,
                                                           const int* __restrict__ pos,
                                                           const int* __restrict__ neg,
                                                           const float* __restrict__ Wgc,
                                                           const float* __restrict__ bgc,
                                                           const float* __restrict__ Wbi,
                                                           const float* __restrict__ bbi,
                                                           float* __restrict__ out,
                                                           int layer) {
    __shared__ float lwgc[64 * 64];
    __shared__ float lwbi[64 * 64];
    const int t = threadIdx.x;
    const int lane = t & 63;
    const int r = blockIdx.x * 16 + (t >> 6);          // grid = 768 -> 12288 rows

    const float* Wg = Wgc + layer * EMB * EMB;
    const float* Wb = Wbi + layer * EMB * EMB;
    for (int idx = t; idx < 64 * 64; idx += 1024) {
        lwgc[idx] = Wg[idx];
        lwbi[idx] = Wb[idx];
    }
    __syncthreads();

    const int seg = r >> 12, idx = r & (BATCH - 1);
    const int node = (seg == 0) ? users[idx] : N_USER + ((seg == 1) ? pos[idx] : neg[idx]);

    float x, inv;
    node_compute(node, row_start, ecv, ego_in, lwgc, lwbi, bgc, bbi, layer, lane, x, inv);
    out[(size_t)r * 256 + (layer + 1) * 64 + lane] = x * inv;
}

// ---- gather one 64-col slice for the 12288 sampled rows into out (row stride 256) ----
__global__ __launch_bounds__(256) void gather_layer(const int* __restrict__ users,
                                                    const int* __restrict__ pos,
                                                    const int* __restrict__ neg,
                                                    const float* __restrict__ src_u,
                                                    const float* __restrict__ src_i,
                                                    const float* __restrict__ inv,
                                                    float* __restrict__ out,
                                                    int col0) {
    int t = blockIdx.x * 256 + threadIdx.x;
    if (t >= NSAMP * EMB) return;
    int r = t >> 6, d = t & 63;
    int seg = r >> 12, idx = r & (BATCH - 1);
    int node = (seg == 0) ? users[idx] : N_USER + ((seg == 1) ? pos[idx] : neg[idx]);
    float v;
    if (inv) {
        v = src_u[(size_t)node * EMB + d] * inv[node];
    } else {
        v = (node < N_USER) ? src_u[(size_t)node * EMB + d]
                            : src_i[(size_t)(node - N_USER) * EMB + d];
    }
    out[(size_t)r * 256 + col0 + d] = v;
}

extern "C" void kernel_launch(void* const* d_in, const int* in_sizes, int n_in,
                              void* d_out, int out_size, void* d_ws, size_t ws_size,
                              hipStream_t stream) {
    const int* users = (const int*)d_in[0];
    const int* pos   = (const int*)d_in[1];
    const int* neg   = (const int*)d_in[2];
    const int* arow  = (const int*)d_in[3];
    const int* acol  = (const int*)d_in[4];
    const float* aval = (const float*)d_in[5];
    const float* ue   = (const float*)d_in[6];
    const float* ie   = (const float*)d_in[7];
    const float* Wgc  = (const float*)d_in[8];
    const float* bgc  = (const float*)d_in[9];
    const float* Wbi  = (const float*)d_in[10];
    const float* bbi  = (const float*)d_in[11];
    float* out = (float*)d_out;

    char* ws = (char*)d_ws;
    const size_t egoBytes = (size_t)N_NODES * EMB * sizeof(float);   // 38,400,000 B
    float* ego_a     = (float*)(ws);
    float* ego_b     = (float*)(ws + egoBytes);
    int2*  ecv       = (int2*)(ws + 2 * egoBytes);                   // 19.2 MB
    int*   row_start = (int*)(ws + 2 * egoBytes + 19200000);         // 600 KB (+pad)
    int*   cursor    = (int*)(ws + 2 * egoBytes + 19200000 + 600064);
    float* inv       = (float*)(ws + 2 * egoBytes + 19200000 + 2 * 600064);
    int*   partials  = (int*)(ws + 2 * egoBytes + 19200000 + 3 * 600064);

    // ---- CSR build (graph reused across all 3 layers) ----
    int* row_cnt = cursor;
    hipMemsetAsync(row_cnt, 0, N_NODES * sizeof(int), stream);
    hist<<<NNZ / 256, 256, 0, stream>>>(arow, row_cnt);
    scan_k1<<<SCAN_BLOCKS, 256, 0, stream>>>(row_cnt, row_start, partials);
    scan_k2<<<1, 1024, 0, stream>>>(partials, SCAN_BLOCKS);
    scan_k3<<<SCAN_BLOCKS, 256, 0, stream>>>(row_start, partials, cursor);
    scatter_edges<<<NNZ / 256, 256, 0, stream>>>(arow, acol, aval, cursor, ecv);

    // ---- embeddings ----
    init_ego<<<(N_NODES * EMB / 4 + 255) / 256, 256, 0, stream>>>(
        (const float4*)ue, (const float4*)ie, (float4*)ego_a);

    gather_layer<<<(NSAMP * EMB) / 256, 256, 0, stream>>>(
        users, pos, neg, ue, ie, nullptr, out, 0);

    // layer 1: ego_a -> ego_b; layer 2: ego_b -> ego_a
    spmm_dense<<<N_NODES / 16, 1024, 0, stream>>>(
        row_start, ecv, ego_a, ego_b, Wgc, bgc, Wbi, bbi, inv, 0);
    gather_layer<<<(NSAMP * EMB) / 256, 256, 0, stream>>>(
        users, pos, neg, ego_b, nullptr, inv, out, 64);

    spmm_dense<<<N_NODES / 16, 1024, 0, stream>>>(
        row_start, ecv, ego_b, ego_a, Wgc, bgc, Wbi, bbi, inv, 1);
    gather_layer<<<(NSAMP * EMB) / 256, 256, 0, stream>>>(
        users, pos, neg, ego_a, nullptr, inv, out, 128);

    // layer 3: only the sampled rows, straight into out
    spmm_dense_sampled<<<NSAMP / 16, 1024, 0, stream>>>(
        row_start, ecv, ego_a, users, pos, neg, Wgc, bgc, Wbi, bbi, out, 2);
}

// Round 6
// 999.020 us; speedup vs baseline: 1.1774x; 1.1774x over previous
//
#include <hip/hip_runtime.h>

#define N_USER 50000
#define N_ITEM 100000
#define N_NODES 150000
#define EMB 64
#define NNZ 2400000
#define BATCH 4096
#define NSAMP (3 * BATCH)                     // 12288 sampled rows
#define SCAN_BLOCKS ((N_NODES + 255) / 256)   // 586

// bf16 round-to-nearest-even of a float, returned in the high 16 bits position
__device__ __forceinline__ unsigned int bf16_rne(float x) {
    unsigned int u = __float_as_uint(x);
    unsigned int r = u + 0x7fffu + ((u >> 16) & 1u);
    return r >> 16;                            // low 16 bits hold the bf16
}

// ---------------- init: ego = concat(user_emb, item_emb), float4 copy ----------------
__global__ __launch_bounds__(256) void init_ego(const float4* __restrict__ ue,
                                                const float4* __restrict__ ie,
                                                float4* __restrict__ ego) {
    int i = blockIdx.x * 256 + threadIdx.x;
    if (i >= N_NODES * EMB / 4) return;
    const int NU4 = N_USER * EMB / 4;
    ego[i] = (i < NU4) ? ue[i] : ie[i - NU4];
}

// ---------------- CSR build ----------------
__global__ __launch_bounds__(256) void hist(const int* __restrict__ rows, int* __restrict__ cnt) {
    int e = blockIdx.x * 256 + threadIdx.x;
    if (e < NNZ) atomicAdd(&cnt[rows[e]], 1);
}

__global__ __launch_bounds__(256) void scan_k1(const int* __restrict__ cnt,
                                               int* __restrict__ row_start,
                                               int* __restrict__ partials) {
    __shared__ int s[256];
    int t = threadIdx.x, i = blockIdx.x * 256 + t;
    int v = (i < N_NODES) ? cnt[i] : 0;
    s[t] = v;
    for (int off = 1; off < 256; off <<= 1) {
        __syncthreads();
        int add = (t >= off) ? s[t - off] : 0;
        __syncthreads();
        s[t] += add;
    }
    if (i < N_NODES) row_start[i] = s[t] - v;
    if (t == 255) partials[blockIdx.x] = s[255];
}

__global__ __launch_bounds__(1024) void scan_k2(int* __restrict__ partials, int nb) {
    __shared__ int s[1024];
    int t = threadIdx.x;
    int v = (t < nb) ? partials[t] : 0;
    s[t] = v;
    for (int off = 1; off < 1024; off <<= 1) {
        __syncthreads();
        int add = (t >= off) ? s[t - off] : 0;
        __syncthreads();
        s[t] += add;
    }
    if (t < nb) partials[t] = s[t] - v;
}

__global__ __launch_bounds__(256) void scan_k3(int* __restrict__ row_start,
                                               const int* __restrict__ partials,
                                               int* __restrict__ cursor) {
    int i = blockIdx.x * 256 + threadIdx.x;
    if (i < N_NODES) {
        int v = row_start[i] + partials[blockIdx.x];
        row_start[i] = v;
        cursor[i] = v;
    }
    if (i == 0) row_start[N_NODES] = NNZ;
}

__global__ __launch_bounds__(256) void scatter_edges(const int* __restrict__ rows,
                                                     const int* __restrict__ cols,
                                                     const float* __restrict__ vals,
                                                     int* __restrict__ cursor,
                                                     int2* __restrict__ ecv) {
    int e = blockIdx.x * 256 + threadIdx.x;
    if (e >= NNZ) return;
    int pos = atomicAdd(&cursor[rows[e]], 1);
    ecv[pos] = make_int2(cols[e], __float_as_int(vals[e]));
}

// ======== core per-node compute: dynamic-trip CSR gather-reduce + dense (bf16-packed W) ========
// lw[jd*64+lane] = (bf16(Wbi[jd][lane]) << 16) | bf16(Wgc[jd][lane])
__device__ __forceinline__ void node_compute(int node,
                                             const int* __restrict__ row_start,
                                             const int2* __restrict__ ecv,
                                             const float* __restrict__ ego_in,
                                             const unsigned int* __restrict__ lw,
                                             const float* __restrict__ bgc,
                                             const float* __restrict__ bbi,
                                             int layer, int lane,
                                             float& x_out, float& inv_out) {
    const int j = lane >> 4;            // edge slot within quad (0..3)
    const int g = (lane & 15) << 2;     // dim offset (float4 group)
    const int s0 = row_start[node];
    const int s1 = row_start[node + 1];

    // hoisted: self-row + biases overlap with the gather loop
    const size_t base = (size_t)node * EMB;
    const float4 e4 = *(const float4*)(ego_in + base + g);
    const float bias = bgc[layer * 64 + lane] + bbi[layer * 64 + lane];

    float4 acc0 = make_float4(0.f, 0.f, 0.f, 0.f);
    float4 acc1 = make_float4(0.f, 0.f, 0.f, 0.f);
    for (int e0 = s0; e0 < s1; e0 += 64) {
        const int cnt = min(64, s1 - e0);
        int2 m = make_int2(0, 0);                      // zero-fill => maskless tail
        if (lane < cnt) m = ecv[e0 + lane];
        for (int jj = 0; jj < cnt; jj += 8) {          // dynamic trip: exact work (d̄=16 → ~2 iters)
            int   i0 = jj + j;
            int   c0 = __shfl(m.x, i0);
            float v0 = __int_as_float(__shfl(m.y, i0));
            const float4 x0 = *(const float4*)(ego_in + (size_t)c0 * EMB + g);
            int   i1 = jj + 4 + j;
            int   c1 = __shfl(m.x, i1);
            float v1 = __int_as_float(__shfl(m.y, i1));
            const float4 x1 = *(const float4*)(ego_in + (size_t)c1 * EMB + g);
            acc0.x = fmaf(v0, x0.x, acc0.x); acc0.y = fmaf(v0, x0.y, acc0.y);
            acc0.z = fmaf(v0, x0.z, acc0.z); acc0.w = fmaf(v0, x0.w, acc0.w);
            acc1.x = fmaf(v1, x1.x, acc1.x); acc1.y = fmaf(v1, x1.y, acc1.y);
            acc1.z = fmaf(v1, x1.z, acc1.z); acc1.w = fmaf(v1, x1.w, acc1.w);
        }
    }
    float av[4] = { acc0.x + acc1.x, acc0.y + acc1.y, acc0.z + acc1.z, acc0.w + acc1.w };
#pragma unroll
    for (int c = 0; c < 4; ++c) {
        av[c] += __shfl_xor(av[c], 16);
        av[c] += __shfl_xor(av[c], 32);
    }
    // every lane holds side[node][4*(lane&15)+c] in av[c]

    float cv[4] = { e4.x * av[0], e4.y * av[1], e4.z * av[2], e4.w * av[3] };

    float acc = bias;
#pragma unroll
    for (int jq = 0; jq < 16; ++jq) {
#pragma unroll
        for (int c = 0; c < 4; ++c) {
            const int jd = jq * 4 + c;
            float bj = __shfl(av[c], jq);              // constant-lane broadcast
            float dj = __shfl(cv[c], jq);
            unsigned int p = lw[jd * 64 + lane];
            float wg = __uint_as_float(p << 16);       // bf16 -> f32: shift to high bits
            float wb = __uint_as_float(p & 0xffff0000u);
            acc = fmaf(bj, wg, acc);
            acc = fmaf(dj, wb, acc);
        }
    }
    float x = (acc >= 0.f) ? acc : 0.2f * acc;         // leaky_relu 0.2

    float s = x * x;                                   // wave-64 L2 norm
#pragma unroll
    for (int off = 32; off > 0; off >>= 1) s += __shfl_xor(s, off);
    x_out = x;
    inv_out = 1.0f / fmaxf(sqrtf(s), 1e-12f);
}

// stage packed weights: 16 KB LDS -> 8 blocks/CU wave cap (100% occupancy)
__device__ __forceinline__ void stage_weights(unsigned int* lw,
                                              const float* __restrict__ Wgc,
                                              const float* __restrict__ Wbi,
                                              int layer, int t) {
    const float* Wg = Wgc + layer * EMB * EMB;
    const float* Wb = Wbi + layer * EMB * EMB;
    for (int idx = t; idx < 64 * 64; idx += 256) {
        unsigned int pg = bf16_rne(Wg[idx]);
        unsigned int pb = bf16_rne(Wb[idx]);
        lw[idx] = (pb << 16) | pg;
    }
}

// ---- full-layer fused kernel: all 150000 nodes, writes ego_out + inv_norm ----
__global__ __launch_bounds__(256) void spmm_dense(const int* __restrict__ row_start,
                                                  const int2* __restrict__ ecv,
                                                  const float* __restrict__ ego_in,
                                                  float* __restrict__ ego_out,
                                                  const float* __restrict__ Wgc,
                                                  const float* __restrict__ bgc,
                                                  const float* __restrict__ Wbi,
                                                  const float* __restrict__ bbi,
                                                  float* __restrict__ inv_norm,
                                                  int layer) {
    __shared__ unsigned int lw[64 * 64];               // 16 KB
    const int t = threadIdx.x;
    const int lane = t & 63;
    const int node = blockIdx.x * 4 + (t >> 6);        // grid = 37500

    stage_weights(lw, Wgc, Wbi, layer, t);
    __syncthreads();

    float x, inv;
    node_compute(node, row_start, ecv, ego_in, lw, bgc, bbi, layer, lane, x, inv);
    ego_out[(size_t)node * EMB + lane] = x;
    if (lane == 0) inv_norm[node] = inv;
}

// ---- last-layer kernel: only the 12288 sampled rows, writes normalized slice into out ----
__global__ __launch_bounds__(256) void spmm_dense_sampled(const int* __restrict__ row_start,
                                                          const int2* __restrict__ ecv,
                                                          const float* __restrict__ ego_in,
                                                          const int* __restrict__ users,
                                                          const int* __restrict__ pos,
                                                          const int* __restrict__ neg,
                                                          const float* __restrict__ Wgc,
                                                          const float* __restrict__ bgc,
                                                          const float* __restrict__ Wbi,
                                                          const float* __restrict__ bbi,
                                                          float* __restrict__ out,
                                                          int layer) {
    __shared__ unsigned int lw[64 * 64];               // 16 KB
    const int t = threadIdx.x;
    const int lane = t & 63;
    const int r = blockIdx.x * 4 + (t >> 6);           // grid = 3072 -> 12288 rows

    stage_weights(lw, Wgc, Wbi, layer, t);
    __syncthreads();

    const int seg = r >> 12, idx = r & (BATCH - 1);
    const int node = (seg == 0) ? users[idx] : N_USER + ((seg == 1) ? pos[idx] : neg[idx]);

    float x, inv;
    node_compute(node, row_start, ecv, ego_in, lw, bgc, bbi, layer, lane, x, inv);
    out[(size_t)r * 256 + (layer + 1) * 64 + lane] = x * inv;
}

// ---- gather one 64-col slice for the 12288 sampled rows into out (row stride 256) ----
__global__ __launch_bounds__(256) void gather_layer(const int* __restrict__ users,
                                                    const int* __restrict__ pos,
                                                    const int* __restrict__ neg,
                                                    const float* __restrict__ src_u,
                                                    const float* __restrict__ src_i,
                                                    const float* __restrict__ inv,
                                                    float* __restrict__ out,
                                                    int col0) {
    int t = blockIdx.x * 256 + threadIdx.x;
    if (t >= NSAMP * EMB) return;
    int r = t >> 6, d = t & 63;
    int seg = r >> 12, idx = r & (BATCH - 1);
    int node = (seg == 0) ? users[idx] : N_USER + ((seg == 1) ? pos[idx] : neg[idx]);
    float v;
    if (inv) {
        v = src_u[(size_t)node * EMB + d] * inv[node];
    } else {
        v = (node < N_USER) ? src_u[(size_t)node * EMB + d]
                            : src_i[(size_t)(node - N_USER) * EMB + d];
    }
    out[(size_t)r * 256 + col0 + d] = v;
}

extern "C" void kernel_launch(void* const* d_in, const int* in_sizes, int n_in,
                              void* d_out, int out_size, void* d_ws, size_t ws_size,
                              hipStream_t stream) {
    const int* users = (const int*)d_in[0];
    const int* pos   = (const int*)d_in[1];
    const int* neg   = (const int*)d_in[2];
    const int* arow  = (const int*)d_in[3];
    const int* acol  = (const int*)d_in[4];
    const float* aval = (const float*)d_in[5];
    const float* ue   = (const float*)d_in[6];
    const float* ie   = (const float*)d_in[7];
    const float* Wgc  = (const float*)d_in[8];
    const float* bgc  = (const float*)d_in[9];
    const float* Wbi  = (const float*)d_in[10];
    const float* bbi  = (const float*)d_in[11];
    float* out = (float*)d_out;

    char* ws = (char*)d_ws;
    const size_t egoBytes = (size_t)N_NODES * EMB * sizeof(float);   // 38,400,000 B
    float* ego_a     = (float*)(ws);
    float* ego_b     = (float*)(ws + egoBytes);
    int2*  ecv       = (int2*)(ws + 2 * egoBytes);                   // 19.2 MB
    int*   row_start = (int*)(ws + 2 * egoBytes + 19200000);         // 600 KB (+pad)
    int*   cursor    = (int*)(ws + 2 * egoBytes + 19200000 + 600064);
    float* inv       = (float*)(ws + 2 * egoBytes + 19200000 + 2 * 600064);
    int*   partials  = (int*)(ws + 2 * egoBytes + 19200000 + 3 * 600064);

    // ---- CSR build (graph reused across all 3 layers) ----
    int* row_cnt = cursor;
    hipMemsetAsync(row_cnt, 0, N_NODES * sizeof(int), stream);
    hist<<<NNZ / 256, 256, 0, stream>>>(arow, row_cnt);
    scan_k1<<<SCAN_BLOCKS, 256, 0, stream>>>(row_cnt, row_start, partials);
    scan_k2<<<1, 1024, 0, stream>>>(partials, SCAN_BLOCKS);
    scan_k3<<<SCAN_BLOCKS, 256, 0, stream>>>(row_start, partials, cursor);
    scatter_edges<<<NNZ / 256, 256, 0, stream>>>(arow, acol, aval, cursor, ecv);

    // ---- embeddings ----
    init_ego<<<(N_NODES * EMB / 4 + 255) / 256, 256, 0, stream>>>(
        (const float4*)ue, (const float4*)ie, (float4*)ego_a);

    gather_layer<<<(NSAMP * EMB) / 256, 256, 0, stream>>>(
        users, pos, neg, ue, ie, nullptr, out, 0);

    // layer 1: ego_a -> ego_b; layer 2: ego_b -> ego_a
    spmm_dense<<<N_NODES / 4, 256, 0, stream>>>(
        row_start, ecv, ego_a, ego_b, Wgc, bgc, Wbi, bbi, inv, 0);
    gather_layer<<<(NSAMP * EMB) / 256, 256, 0, stream>>>(
        users, pos, neg, ego_b, nullptr, inv, out, 64);

    spmm_dense<<<N_NODES / 4, 256, 0, stream>>>(
        row_start, ecv, ego_b, ego_a, Wgc, bgc, Wbi, bbi, inv, 1);
    gather_layer<<<(NSAMP * EMB) / 256, 256, 0, stream>>>(
        users, pos, neg, ego_a, nullptr, inv, out, 128);

    // layer 3: only the sampled rows, straight into out
    spmm_dense_sampled<<<NSAMP / 4, 256, 0, stream>>>(
        row_start, ecv, ego_a, users, pos, neg, Wgc, bgc, Wbi, bbi, out, 2);
}

// Round 7
// 583.095 us; speedup vs baseline: 2.0172x; 1.7133x over previous
//
#include <hip/hip_runtime.h>

typedef short bf16x8 __attribute__((ext_vector_type(8)));
typedef float f32x4  __attribute__((ext_vector_type(4)));

#define N_USER 50000
#define N_ITEM 100000
#define N_NODES 150000
#define EMB 64
#define NNZ 2400000
#define BATCH 4096
#define NSAMP (3 * BATCH)                     // 12288 sampled rows
#define SCAN_BLOCKS ((N_NODES + 255) / 256)   // 586

// bf16 round-to-nearest-even; low 16 bits hold the bf16
__device__ __forceinline__ unsigned int bf16_rne(float x) {
    unsigned int u = __float_as_uint(x);
    return (u + 0x7fffu + ((u >> 16) & 1u)) >> 16;
}
__device__ __forceinline__ float bflo(unsigned int u) { return __uint_as_float(u << 16); }
__device__ __forceinline__ float bfhi(unsigned int u) { return __uint_as_float(u & 0xffff0000u); }

__device__ __forceinline__ void fma8(float v, const uint4& x, float* acc) {
    acc[0] = fmaf(v, bflo(x.x), acc[0]); acc[1] = fmaf(v, bfhi(x.x), acc[1]);
    acc[2] = fmaf(v, bflo(x.y), acc[2]); acc[3] = fmaf(v, bfhi(x.y), acc[3]);
    acc[4] = fmaf(v, bflo(x.z), acc[4]); acc[5] = fmaf(v, bfhi(x.z), acc[5]);
    acc[6] = fmaf(v, bflo(x.w), acc[6]); acc[7] = fmaf(v, bfhi(x.w), acc[7]);
}
__device__ __forceinline__ uint4 pack8(const float* f) {
    return make_uint4((bf16_rne(f[1]) << 16) | bf16_rne(f[0]),
                      (bf16_rne(f[3]) << 16) | bf16_rne(f[2]),
                      (bf16_rne(f[5]) << 16) | bf16_rne(f[4]),
                      (bf16_rne(f[7]) << 16) | bf16_rne(f[6]));
}

// ---------------- init: ego_bf = bf16(concat(user_emb, item_emb)) ----------------
__global__ __launch_bounds__(256) void init_ego_bf(const float4* __restrict__ ue,
                                                   const float4* __restrict__ ie,
                                                   uint2* __restrict__ ego_bf) {
    int i = blockIdx.x * 256 + threadIdx.x;            // over N_NODES*16 float4
    if (i >= N_NODES * 16) return;
    const int NU4 = N_USER * 16;
    float4 v = (i < NU4) ? ue[i] : ie[i - NU4];
    ego_bf[i] = make_uint2((bf16_rne(v.y) << 16) | bf16_rne(v.x),
                           (bf16_rne(v.w) << 16) | bf16_rne(v.z));
}

// ---------------- CSR build ----------------
__global__ __launch_bounds__(256) void hist(const int* __restrict__ rows, int* __restrict__ cnt) {
    int e = blockIdx.x * 256 + threadIdx.x;
    if (e < NNZ) atomicAdd(&cnt[rows[e]], 1);
}

__global__ __launch_bounds__(256) void scan_k1(const int* __restrict__ cnt,
                                               int* __restrict__ row_start,
                                               int* __restrict__ partials) {
    __shared__ int s[256];
    int t = threadIdx.x, i = blockIdx.x * 256 + t;
    int v = (i < N_NODES) ? cnt[i] : 0;
    s[t] = v;
    for (int off = 1; off < 256; off <<= 1) {
        __syncthreads();
        int add = (t >= off) ? s[t - off] : 0;
        __syncthreads();
        s[t] += add;
    }
    if (i < N_NODES) row_start[i] = s[t] - v;
    if (t == 255) partials[blockIdx.x] = s[255];
}

__global__ __launch_bounds__(1024) void scan_k2(int* __restrict__ partials, int nb) {
    __shared__ int s[1024];
    int t = threadIdx.x;
    int v = (t < nb) ? partials[t] : 0;
    s[t] = v;
    for (int off = 1; off < 1024; off <<= 1) {
        __syncthreads();
        int add = (t >= off) ? s[t - off] : 0;
        __syncthreads();
        s[t] += add;
    }
    if (t < nb) partials[t] = s[t] - v;
}

__global__ __launch_bounds__(256) void scan_k3(int* __restrict__ row_start,
                                               const int* __restrict__ partials,
                                               int* __restrict__ cursor) {
    int i = blockIdx.x * 256 + threadIdx.x;
    if (i < N_NODES) {
        int v = row_start[i] + partials[blockIdx.x];
        row_start[i] = v;
        cursor[i] = v;
    }
    if (i == 0) row_start[N_NODES] = NNZ;
}

__global__ __launch_bounds__(256) void scatter_edges(const int* __restrict__ rows,
                                                     const int* __restrict__ cols,
                                                     const float* __restrict__ vals,
                                                     int* __restrict__ cursor,
                                                     int2* __restrict__ ecv) {
    int e = blockIdx.x * 256 + threadIdx.x;
    if (e >= NNZ) return;
    int pos = atomicAdd(&cursor[rows[e]], 1);
    ecv[pos] = make_int2(cols[e], __float_as_int(vals[e]));
}

// ---- sampled node list ----
__global__ __launch_bounds__(256) void build_samp(const int* __restrict__ users,
                                                  const int* __restrict__ pos,
                                                  const int* __restrict__ neg,
                                                  int* __restrict__ samp) {
    int t = blockIdx.x * 256 + threadIdx.x;
    if (t >= NSAMP) return;
    int seg = t >> 12, idx = t & (BATCH - 1);
    samp[t] = (seg == 0) ? users[idx] : N_USER + ((seg == 1) ? pos[idx] : neg[idx]);
}

// ======== kernel 1: CSR gather-reduce (bf16 ego) -> side_cs[r] = [side(64) | ego*side(64)] bf16 ====
// wave per row; 8 groups of 8 lanes; each lane holds 8 dims; 8 edges per load instruction
__global__ __launch_bounds__(256) void spmm_gather(const int* __restrict__ row_start,
                                                   const int2* __restrict__ ecv,
                                                   const uint4* __restrict__ ego_bf, // 8 uint4/row
                                                   ushort* __restrict__ side_cs,    // n_rows x 128 bf16
                                                   const int* __restrict__ node_list,
                                                   int n_rows) {
    const int t = threadIdx.x;
    const int lane = t & 63;
    const int r = blockIdx.x * 4 + (t >> 6);
    if (r >= n_rows) return;
    const int node = node_list ? node_list[r] : r;
    const int j8 = lane >> 3;
    const int g8 = lane & 7;

    const int s0 = row_start[node];
    const int s1 = row_start[node + 1];
    const uint4 selfv = ego_bf[(size_t)node * 8 + g8];

    float acc[8] = {0.f, 0.f, 0.f, 0.f, 0.f, 0.f, 0.f, 0.f};
    for (int e0 = s0; e0 < s1; e0 += 64) {
        const int cnt = min(64, s1 - e0);
        int2 m = make_int2(0, 0);                      // zero-fill: pad slots are no-ops
        if (lane < cnt) m = ecv[e0 + lane];
        for (int jj = 0; jj < cnt; jj += 16) {         // 16 edges per iter (2 x 8-wide loads)
            int   i0 = jj + j8;
            int   c0 = __shfl(m.x, i0);
            float v0 = __int_as_float(__shfl(m.y, i0));
            const uint4 x0 = ego_bf[(size_t)c0 * 8 + g8];
            int   i1 = jj + 8 + j8;
            int   c1 = __shfl(m.x, i1);
            float v1 = __int_as_float(__shfl(m.y, i1));
            const uint4 x1 = ego_bf[(size_t)c1 * 8 + g8];
            fma8(v0, x0, acc);
            fma8(v1, x1, acc);
        }
    }
    // reduce across the 8 edge-slot groups (lane bits 3,4,5)
#pragma unroll
    for (int c = 0; c < 8; ++c) {
        acc[c] += __shfl_xor(acc[c], 8);
        acc[c] += __shfl_xor(acc[c], 16);
        acc[c] += __shfl_xor(acc[c], 32);
    }
    // every lane now holds side[node][g8*8 + 0..7] in acc[]

    uint4* scs4 = (uint4*)side_cs;                     // row = 16 uint4 (256 B)
    if (j8 == 0) {
        scs4[(size_t)r * 16 + g8] = pack8(acc);        // side half
    } else if (j8 == 1) {
        float cs[8] = { bflo(selfv.x) * acc[0], bfhi(selfv.x) * acc[1],
                        bflo(selfv.y) * acc[2], bfhi(selfv.y) * acc[3],
                        bflo(selfv.z) * acc[4], bfhi(selfv.z) * acc[5],
                        bflo(selfv.w) * acc[6], bfhi(selfv.w) * acc[7] };
        scs4[(size_t)r * 16 + 8 + g8] = pack8(cs);     // ego*side half
    }
}

// ======== kernel 2: MFMA GEMM [n_rows x 128]_bf16 @ [128 x 64] + bias + leaky + row-norm ========
// mode 0: write ego_out (bf16, pre-norm) + inv_norm;  mode 1: write x*inv (f32) into out at col0
#define WROW 136   // padded LDS row (bf16 elems): 272 B -> bank stride 4
__global__ __launch_bounds__(256) void gemm_dense(const ushort* __restrict__ side_cs,
                                                  const float* __restrict__ Wgc,
                                                  const float* __restrict__ bgc,
                                                  const float* __restrict__ Wbi,
                                                  const float* __restrict__ bbi,
                                                  ushort* __restrict__ ego_out,
                                                  float* __restrict__ inv_norm,
                                                  float* __restrict__ out,
                                                  int n_rows, int layer, int out_mode, int col0) {
    __shared__ ushort wT[64 * WROW];                   // wT[n][k] = Wstack[k][n], bf16
    const int t = threadIdx.x;
    const float* Wg = Wgc + layer * 4096;
    const float* Wb = Wbi + layer * 4096;
    for (int idx = t; idx < 8192; idx += 256) {
        int n = idx >> 7, k = idx & 127;
        float w = (k < 64) ? Wg[k * 64 + n] : Wb[(k - 64) * 64 + n];
        wT[n * WROW + k] = (ushort)bf16_rne(w);
    }
    __syncthreads();

    const int lane = t & 63;
    const int wv = t >> 6;
    const int l15 = lane & 15, quad = lane >> 4;

    // B-frags in registers: [kstep][ntile]; B[k=quad*8+j][n=lane&15]
    const bf16x8* wt8 = (const bf16x8*)wT;             // row stride WROW/8 = 17
    bf16x8 bfr[4][4];
#pragma unroll
    for (int ks = 0; ks < 4; ++ks)
#pragma unroll
        for (int nt = 0; nt < 4; ++nt)
            bfr[ks][nt] = wt8[(nt * 16 + l15) * 17 + ks * 4 + quad];

    float bias[4];
#pragma unroll
    for (int nt = 0; nt < 4; ++nt) {
        int ccol = nt * 16 + l15;
        bias[nt] = bgc[layer * 64 + ccol] + bbi[layer * 64 + ccol];
    }

    const bf16x8* sc8 = (const bf16x8*)side_cs;        // row stride 16

    for (int i = 0; i < 4; ++i) {
        int tile = (blockIdx.x * 4 + wv) * 4 + i;
        int n0 = tile * 16;
        if (n0 >= n_rows) break;
        int mrow = n0 + l15;
        if (mrow >= n_rows) mrow = n_rows - 1;         // clamp; results masked at store

        f32x4 acc[4] = {{0,0,0,0}, {0,0,0,0}, {0,0,0,0}, {0,0,0,0}};
#pragma unroll
        for (int ks = 0; ks < 4; ++ks) {
            bf16x8 afr = sc8[(size_t)mrow * 16 + ks * 4 + quad];  // A[m=lane&15][k=quad*8+j]
#pragma unroll
            for (int nt = 0; nt < 4; ++nt)
                acc[nt] = __builtin_amdgcn_mfma_f32_16x16x32_bf16(afr, bfr[ks][nt], acc[nt], 0, 0, 0);
        }

        // epilogue: bias + leaky + row L2-norm. C/D: col=lane&15, row=quad*4+reg
        float x[4][4];
        float ss[4] = {0.f, 0.f, 0.f, 0.f};
#pragma unroll
        for (int nt = 0; nt < 4; ++nt)
#pragma unroll
            for (int rg = 0; rg < 4; ++rg) {
                float v = acc[nt][rg] + bias[nt];
                v = (v >= 0.f) ? v : 0.2f * v;
                x[nt][rg] = v;
                ss[rg] = fmaf(v, v, ss[rg]);
            }
#pragma unroll
        for (int rg = 0; rg < 4; ++rg) {
            ss[rg] += __shfl_xor(ss[rg], 1);
            ss[rg] += __shfl_xor(ss[rg], 2);
            ss[rg] += __shfl_xor(ss[rg], 4);
            ss[rg] += __shfl_xor(ss[rg], 8);
        }
#pragma unroll
        for (int rg = 0; rg < 4; ++rg) {
            int row = n0 + quad * 4 + rg;
            if (row >= n_rows) continue;
            float invr = 1.0f / fmaxf(sqrtf(ss[rg]), 1e-12f);
            if (out_mode) {
#pragma unroll
                for (int nt = 0; nt < 4; ++nt)
                    out[(size_t)row * 256 + col0 + nt * 16 + l15] = x[nt][rg] * invr;
            } else {
#pragma unroll
                for (int nt = 0; nt < 4; ++nt)
                    ego_out[(size_t)row * 64 + nt * 16 + l15] = (ushort)bf16_rne(x[nt][rg]);
                if (l15 == 0) inv_norm[row] = invr;
            }
        }
    }
}

// ---- layer-0 output slice: raw fp32 embeddings of sampled rows ----
__global__ __launch_bounds__(256) void gather0(const int* __restrict__ users,
                                               const int* __restrict__ pos,
                                               const int* __restrict__ neg,
                                               const float* __restrict__ ue,
                                               const float* __restrict__ ie,
                                               float* __restrict__ out) {
    int t = blockIdx.x * 256 + threadIdx.x;
    if (t >= NSAMP * EMB) return;
    int r = t >> 6, d = t & 63;
    int seg = r >> 12, idx = r & (BATCH - 1);
    int node = (seg == 0) ? users[idx] : N_USER + ((seg == 1) ? pos[idx] : neg[idx]);
    float v = (node < N_USER) ? ue[(size_t)node * EMB + d]
                              : ie[(size_t)(node - N_USER) * EMB + d];
    out[(size_t)r * 256 + d] = v;
}

// ---- layers 1,2 output slices: normalized bf16 ego of sampled rows ----
__global__ __launch_bounds__(256) void gather_bf(const int* __restrict__ users,
                                                 const int* __restrict__ pos,
                                                 const int* __restrict__ neg,
                                                 const ushort* __restrict__ ego_bf,
                                                 const float* __restrict__ inv,
                                                 float* __restrict__ out, int col0) {
    int t = blockIdx.x * 256 + threadIdx.x;
    if (t >= NSAMP * EMB) return;
    int r = t >> 6, d = t & 63;
    int seg = r >> 12, idx = r & (BATCH - 1);
    int node = (seg == 0) ? users[idx] : N_USER + ((seg == 1) ? pos[idx] : neg[idx]);
    float v = __uint_as_float(((unsigned int)ego_bf[(size_t)node * 64 + d]) << 16) * inv[node];
    out[(size_t)r * 256 + col0 + d] = v;
}

extern "C" void kernel_launch(void* const* d_in, const int* in_sizes, int n_in,
                              void* d_out, int out_size, void* d_ws, size_t ws_size,
                              hipStream_t stream) {
    const int* users = (const int*)d_in[0];
    const int* pos   = (const int*)d_in[1];
    const int* neg   = (const int*)d_in[2];
    const int* arow  = (const int*)d_in[3];
    const int* acol  = (const int*)d_in[4];
    const float* aval = (const float*)d_in[5];
    const float* ue   = (const float*)d_in[6];
    const float* ie   = (const float*)d_in[7];
    const float* Wgc  = (const float*)d_in[8];
    const float* bgc  = (const float*)d_in[9];
    const float* Wbi  = (const float*)d_in[10];
    const float* bbi  = (const float*)d_in[11];
    float* out = (float*)d_out;

    char* ws = (char*)d_ws;
    const size_t egoBfBytes = (size_t)N_NODES * EMB * 2;        // 19,200,000
    const size_t scsBytes   = (size_t)N_NODES * 128 * 2;        // 38,400,000
    ushort* ego_a   = (ushort*)(ws);
    ushort* ego_b   = (ushort*)(ws + egoBfBytes);
    ushort* side_cs = (ushort*)(ws + 2 * egoBfBytes);
    int2*   ecv     = (int2*)  (ws + 2 * egoBfBytes + scsBytes);
    char*   p       = ws + 2 * egoBfBytes + scsBytes + (size_t)NNZ * 8;
    int*    row_start = (int*)(p);                               // 600,064
    int*    cursor    = (int*)(p + 600064);
    float*  inv       = (float*)(p + 2 * 600064);
    int*    partials  = (int*)(p + 3 * 600064);                  // 4096
    int*    samp      = (int*)(p + 3 * 600064 + 4096);           // 49,152

    // ---- CSR build (graph reused across all 3 layers) ----
    int* row_cnt = cursor;
    hipMemsetAsync(row_cnt, 0, N_NODES * sizeof(int), stream);
    hist<<<NNZ / 256, 256, 0, stream>>>(arow, row_cnt);
    scan_k1<<<SCAN_BLOCKS, 256, 0, stream>>>(row_cnt, row_start, partials);
    scan_k2<<<1, 1024, 0, stream>>>(partials, SCAN_BLOCKS);
    scan_k3<<<SCAN_BLOCKS, 256, 0, stream>>>(row_start, partials, cursor);
    scatter_edges<<<NNZ / 256, 256, 0, stream>>>(arow, acol, aval, cursor, ecv);

    // ---- embeddings + layer-0 slice ----
    init_ego_bf<<<(N_NODES * 16 + 255) / 256, 256, 0, stream>>>(
        (const float4*)ue, (const float4*)ie, (uint2*)ego_a);
    gather0<<<(NSAMP * EMB) / 256, 256, 0, stream>>>(users, pos, neg, ue, ie, out);
    build_samp<<<(NSAMP + 255) / 256, 256, 0, stream>>>(users, pos, neg, samp);

    // ---- layer 1: ego_a -> ego_b ----
    spmm_gather<<<N_NODES / 4, 256, 0, stream>>>(row_start, ecv, (const uint4*)ego_a,
                                                 side_cs, nullptr, N_NODES);
    gemm_dense<<<586, 256, 0, stream>>>(side_cs, Wgc, bgc, Wbi, bbi,
                                        ego_b, inv, nullptr, N_NODES, 0, 0, 0);
    gather_bf<<<(NSAMP * EMB) / 256, 256, 0, stream>>>(users, pos, neg, ego_b, inv, out, 64);

    // ---- layer 2: ego_b -> ego_a ----
    spmm_gather<<<N_NODES / 4, 256, 0, stream>>>(row_start, ecv, (const uint4*)ego_b,
                                                 side_cs, nullptr, N_NODES);
    gemm_dense<<<586, 256, 0, stream>>>(side_cs, Wgc, bgc, Wbi, bbi,
                                        ego_a, inv, nullptr, N_NODES, 1, 0, 0);
    gather_bf<<<(NSAMP * EMB) / 256, 256, 0, stream>>>(users, pos, neg, ego_a, inv, out, 128);

    // ---- layer 3: sampled rows only, straight into out ----
    spmm_gather<<<NSAMP / 4, 256, 0, stream>>>(row_start, ecv, (const uint4*)ego_a,
                                               side_cs, samp, NSAMP);
    gemm_dense<<<48, 256, 0, stream>>>(side_cs, Wgc, bgc, Wbi, bbi,
                                       nullptr, nullptr, out, NSAMP, 2, 1, 192);
}

// Round 8
// 537.568 us; speedup vs baseline: 2.1881x; 1.0847x over previous
//
#include <hip/hip_runtime.h>

typedef short bf16x8 __attribute__((ext_vector_type(8)));
typedef float f32x4  __attribute__((ext_vector_type(4)));

#define N_USER 50000
#define N_ITEM 100000
#define N_NODES 150000
#define EMB 64
#define NNZ 2400000
#define BATCH 4096
#define NSAMP (3 * BATCH)                     // 12288 sampled rows
#define NB 1024                               // row-range buckets
#define RPB 147                               // rows per bucket (1024*147 = 150528 >= 150001)
#define NR 8                                  // cursor replicas per bucket

// bf16 round-to-nearest-even; low 16 bits hold the bf16
__device__ __forceinline__ unsigned int bf16_rne(float x) {
    unsigned int u = __float_as_uint(x);
    return (u + 0x7fffu + ((u >> 16) & 1u)) >> 16;
}
__device__ __forceinline__ float bflo(unsigned int u) { return __uint_as_float(u << 16); }
__device__ __forceinline__ float bfhi(unsigned int u) { return __uint_as_float(u & 0xffff0000u); }

__device__ __forceinline__ void fma8(float v, const uint4& x, float* acc) {
    acc[0] = fmaf(v, bflo(x.x), acc[0]); acc[1] = fmaf(v, bfhi(x.x), acc[1]);
    acc[2] = fmaf(v, bflo(x.y), acc[2]); acc[3] = fmaf(v, bfhi(x.y), acc[3]);
    acc[4] = fmaf(v, bflo(x.z), acc[4]); acc[5] = fmaf(v, bfhi(x.z), acc[5]);
    acc[6] = fmaf(v, bflo(x.w), acc[6]); acc[7] = fmaf(v, bfhi(x.w), acc[7]);
}
__device__ __forceinline__ uint4 pack8(const float* f) {
    return make_uint4((bf16_rne(f[1]) << 16) | bf16_rne(f[0]),
                      (bf16_rne(f[3]) << 16) | bf16_rne(f[2]),
                      (bf16_rne(f[5]) << 16) | bf16_rne(f[4]),
                      (bf16_rne(f[7]) << 16) | bf16_rne(f[6]));
}

// ---------------- init: ego_bf = bf16(concat(user_emb, item_emb)) ----------------
__global__ __launch_bounds__(256) void init_ego_bf(const float4* __restrict__ ue,
                                                   const float4* __restrict__ ie,
                                                   uint2* __restrict__ ego_bf) {
    int i = blockIdx.x * 256 + threadIdx.x;            // over N_NODES*16 float4
    if (i >= N_NODES * 16) return;
    const int NU4 = N_USER * 16;
    float4 v = (i < NU4) ? ue[i] : ie[i - NU4];
    ego_bf[i] = make_uint2((bf16_rne(v.y) << 16) | bf16_rne(v.x),
                           (bf16_rne(v.w) << 16) | bf16_rne(v.z));
}

// ================= CSR build, two-phase binned (write-locality-first) =================
// phase A1: count edges per (bucket, replica); replica keyed by blockIdx&7 (XCD affinity)
__global__ __launch_bounds__(256) void bin_count(const int* __restrict__ rows,
                                                 int* __restrict__ bcnt) {
    int e = blockIdx.x * 256 + threadIdx.x;            // grid = NNZ/256 exactly
    int b = rows[e] / RPB;
    atomicAdd(&bcnt[b * NR + (blockIdx.x & 7)], 1);
}

// phase A2: exclusive scan of the 8192 counters (bucket-major); writes boff + working copy bcur
__global__ __launch_bounds__(1024) void scan8k(const int* __restrict__ bcnt,
                                               int* __restrict__ boff,
                                               int* __restrict__ bcur) {
    __shared__ int s[1024];
    const int t = threadIdx.x;
    int v[8], sum = 0;
#pragma unroll
    for (int i = 0; i < 8; ++i) { v[i] = bcnt[t * 8 + i]; sum += v[i]; }
    s[t] = sum;
    for (int off = 1; off < 1024; off <<= 1) {
        __syncthreads();
        int add = (t >= off) ? s[t - off] : 0;
        __syncthreads();
        s[t] += add;
    }
    __syncthreads();
    int ex = s[t] - sum;                               // exclusive base for this thread's 8
#pragma unroll
    for (int i = 0; i < 8; ++i) { boff[t * 8 + i] = ex; bcur[t * 8 + i] = ex; ex += v[i]; }
}

// phase A3: append edges into bucket-contiguous regions (writes dense, line-coalesced)
__global__ __launch_bounds__(256) void bin_scatter(const int* __restrict__ rows,
                                                   const int* __restrict__ cols,
                                                   const float* __restrict__ vals,
                                                   int* __restrict__ bcur,
                                                   int2* __restrict__ tmp_cv,
                                                   int* __restrict__ tmp_row) {
    int e = blockIdx.x * 256 + threadIdx.x;
    int r = rows[e];
    int pos = atomicAdd(&bcur[(r / RPB) * NR + (blockIdx.x & 7)], 1);
    tmp_cv[pos] = make_int2(cols[e], __float_as_int(vals[e]));
    tmp_row[pos] = r;
}

// phase B: one block per bucket — local row histogram+scan in LDS gives CSR order AND
// row_start for free (bucket record base == CSR base: buckets are contiguous row ranges)
__global__ __launch_bounds__(256) void csr_from_bins(const int* __restrict__ boff,
                                                     const int* __restrict__ tmp_row,
                                                     const int2* __restrict__ tmp_cv,
                                                     int2* __restrict__ ecv,
                                                     int* __restrict__ row_start) {
    __shared__ int rcnt[RPB];                          // counts, then reused as cursors
    __shared__ int excl[RPB + 1];
    __shared__ int sc[256];
    const int b = blockIdx.x;
    const int row0 = b * RPB;
    if (row0 > N_NODES) return;                        // buckets fully past the sentinel
    const int t = threadIdx.x;
    const int beg = boff[b * NR];
    const int end = (b == NB - 1) ? NNZ : boff[(b + 1) * NR];

    for (int i = t; i < RPB; i += 256) rcnt[i] = 0;
    __syncthreads();
    for (int i = beg + t; i < end; i += 256) atomicAdd(&rcnt[tmp_row[i] - row0], 1);
    __syncthreads();

    int v = (t < RPB) ? rcnt[t] : 0;                   // block scan over 256 >= RPB
    sc[t] = v;
    for (int off = 1; off < 256; off <<= 1) {
        __syncthreads();
        int add = (t >= off) ? sc[t - off] : 0;
        __syncthreads();
        sc[t] += add;
    }
    __syncthreads();
    if (t < RPB) excl[t] = sc[t] - v;
    if (t == RPB - 1) excl[RPB] = sc[t];
    __syncthreads();

    int lim = N_NODES + 1 - row0;                      // include global sentinel row
    if (lim > RPB) lim = RPB;                          // next bucket writes row_start[row0+RPB]
    for (int i = t; i < lim; i += 256) row_start[row0 + i] = beg + excl[i];
    __syncthreads();
    for (int i = t; i < RPB; i += 256) rcnt[i] = excl[i];   // cursors
    __syncthreads();
    for (int i = beg + t; i < end; i += 256) {         // scatter within ~18 KB L2 window
        int r = tmp_row[i] - row0;
        int dst = beg + atomicAdd(&rcnt[r], 1);
        ecv[dst] = tmp_cv[i];
    }
}

// ---- sampled node list ----
__global__ __launch_bounds__(256) void build_samp(const int* __restrict__ users,
                                                  const int* __restrict__ pos,
                                                  const int* __restrict__ neg,
                                                  int* __restrict__ samp) {
    int t = blockIdx.x * 256 + threadIdx.x;
    if (t >= NSAMP) return;
    int seg = t >> 12, idx = t & (BATCH - 1);
    samp[t] = (seg == 0) ? users[idx] : N_USER + ((seg == 1) ? pos[idx] : neg[idx]);
}

// ======== kernel 1: CSR gather-reduce (bf16 ego) -> side_cs[r] = [side(64) | ego*side(64)] bf16 ====
__global__ __launch_bounds__(256) void spmm_gather(const int* __restrict__ row_start,
                                                   const int2* __restrict__ ecv,
                                                   const uint4* __restrict__ ego_bf, // 8 uint4/row
                                                   ushort* __restrict__ side_cs,    // n_rows x 128 bf16
                                                   const int* __restrict__ node_list,
                                                   int n_rows) {
    const int t = threadIdx.x;
    const int lane = t & 63;
    const int r = blockIdx.x * 4 + (t >> 6);
    if (r >= n_rows) return;
    const int node = node_list ? node_list[r] : r;
    const int j8 = lane >> 3;
    const int g8 = lane & 7;

    const int s0 = row_start[node];
    const int s1 = row_start[node + 1];
    const uint4 selfv = ego_bf[(size_t)node * 8 + g8];

    float acc[8] = {0.f, 0.f, 0.f, 0.f, 0.f, 0.f, 0.f, 0.f};
    for (int e0 = s0; e0 < s1; e0 += 64) {
        const int cnt = min(64, s1 - e0);
        int2 m = make_int2(0, 0);                      // zero-fill: pad slots are no-ops
        if (lane < cnt) m = ecv[e0 + lane];
        for (int jj = 0; jj < cnt; jj += 16) {         // 16 edges per iter (2 x 8-wide loads)
            int   i0 = jj + j8;
            int   c0 = __shfl(m.x, i0);
            float v0 = __int_as_float(__shfl(m.y, i0));
            const uint4 x0 = ego_bf[(size_t)c0 * 8 + g8];
            int   i1 = jj + 8 + j8;
            int   c1 = __shfl(m.x, i1);
            float v1 = __int_as_float(__shfl(m.y, i1));
            const uint4 x1 = ego_bf[(size_t)c1 * 8 + g8];
            fma8(v0, x0, acc);
            fma8(v1, x1, acc);
        }
    }
#pragma unroll
    for (int c = 0; c < 8; ++c) {
        acc[c] += __shfl_xor(acc[c], 8);
        acc[c] += __shfl_xor(acc[c], 16);
        acc[c] += __shfl_xor(acc[c], 32);
    }
    uint4* scs4 = (uint4*)side_cs;                     // row = 16 uint4 (256 B)
    if (j8 == 0) {
        scs4[(size_t)r * 16 + g8] = pack8(acc);        // side half
    } else if (j8 == 1) {
        float cs[8] = { bflo(selfv.x) * acc[0], bfhi(selfv.x) * acc[1],
                        bflo(selfv.y) * acc[2], bfhi(selfv.y) * acc[3],
                        bflo(selfv.z) * acc[4], bfhi(selfv.z) * acc[5],
                        bflo(selfv.w) * acc[6], bfhi(selfv.w) * acc[7] };
        scs4[(size_t)r * 16 + 8 + g8] = pack8(cs);     // ego*side half
    }
}

// ======== kernel 2: MFMA GEMM [n_rows x 128]_bf16 @ [128 x 64] + bias + leaky + row-norm ========
#define WROW 136   // padded LDS row (bf16 elems): 272 B -> bank stride 4
__global__ __launch_bounds__(256) void gemm_dense(const ushort* __restrict__ side_cs,
                                                  const float* __restrict__ Wgc,
                                                  const float* __restrict__ bgc,
                                                  const float* __restrict__ Wbi,
                                                  const float* __restrict__ bbi,
                                                  ushort* __restrict__ ego_out,
                                                  float* __restrict__ inv_norm,
                                                  float* __restrict__ out,
                                                  int n_rows, int layer, int out_mode, int col0) {
    __shared__ ushort wT[64 * WROW];                   // wT[n][k] = Wstack[k][n], bf16
    const int t = threadIdx.x;
    const float* Wg = Wgc + layer * 4096;
    const float* Wb = Wbi + layer * 4096;
    for (int idx = t; idx < 8192; idx += 256) {
        int n = idx >> 7, k = idx & 127;
        float w = (k < 64) ? Wg[k * 64 + n] : Wb[(k - 64) * 64 + n];
        wT[n * WROW + k] = (ushort)bf16_rne(w);
    }
    __syncthreads();

    const int lane = t & 63;
    const int wv = t >> 6;
    const int l15 = lane & 15, quad = lane >> 4;

    const bf16x8* wt8 = (const bf16x8*)wT;             // row stride WROW/8 = 17
    bf16x8 bfr[4][4];
#pragma unroll
    for (int ks = 0; ks < 4; ++ks)
#pragma unroll
        for (int nt = 0; nt < 4; ++nt)
            bfr[ks][nt] = wt8[(nt * 16 + l15) * 17 + ks * 4 + quad];

    float bias[4];
#pragma unroll
    for (int nt = 0; nt < 4; ++nt) {
        int ccol = nt * 16 + l15;
        bias[nt] = bgc[layer * 64 + ccol] + bbi[layer * 64 + ccol];
    }

    const bf16x8* sc8 = (const bf16x8*)side_cs;        // row stride 16

    for (int i = 0; i < 4; ++i) {
        int tile = (blockIdx.x * 4 + wv) * 4 + i;
        int n0 = tile * 16;
        if (n0 >= n_rows) break;
        int mrow = n0 + l15;
        if (mrow >= n_rows) mrow = n_rows - 1;         // clamp; masked at store

        f32x4 acc[4] = {{0,0,0,0}, {0,0,0,0}, {0,0,0,0}, {0,0,0,0}};
#pragma unroll
        for (int ks = 0; ks < 4; ++ks) {
            bf16x8 afr = sc8[(size_t)mrow * 16 + ks * 4 + quad];  // A[m=lane&15][k=quad*8+j]
#pragma unroll
            for (int nt = 0; nt < 4; ++nt)
                acc[nt] = __builtin_amdgcn_mfma_f32_16x16x32_bf16(afr, bfr[ks][nt], acc[nt], 0, 0, 0);
        }

        float x[4][4];
        float ss[4] = {0.f, 0.f, 0.f, 0.f};
#pragma unroll
        for (int nt = 0; nt < 4; ++nt)
#pragma unroll
            for (int rg = 0; rg < 4; ++rg) {
                float v = acc[nt][rg] + bias[nt];
                v = (v >= 0.f) ? v : 0.2f * v;
                x[nt][rg] = v;
                ss[rg] = fmaf(v, v, ss[rg]);
            }
#pragma unroll
        for (int rg = 0; rg < 4; ++rg) {
            ss[rg] += __shfl_xor(ss[rg], 1);
            ss[rg] += __shfl_xor(ss[rg], 2);
            ss[rg] += __shfl_xor(ss[rg], 4);
            ss[rg] += __shfl_xor(ss[rg], 8);
        }
#pragma unroll
        for (int rg = 0; rg < 4; ++rg) {
            int row = n0 + quad * 4 + rg;
            if (row >= n_rows) continue;
            float invr = 1.0f / fmaxf(sqrtf(ss[rg]), 1e-12f);
            if (out_mode) {
#pragma unroll
                for (int nt = 0; nt < 4; ++nt)
                    out[(size_t)row * 256 + col0 + nt * 16 + l15] = x[nt][rg] * invr;
            } else {
#pragma unroll
                for (int nt = 0; nt < 4; ++nt)
                    ego_out[(size_t)row * 64 + nt * 16 + l15] = (ushort)bf16_rne(x[nt][rg]);
                if (l15 == 0) inv_norm[row] = invr;
            }
        }
    }
}

// ---- layer-0 output slice: raw fp32 embeddings of sampled rows ----
__global__ __launch_bounds__(256) void gather0(const int* __restrict__ users,
                                               const int* __restrict__ pos,
                                               const int* __restrict__ neg,
                                               const float* __restrict__ ue,
                                               const float* __restrict__ ie,
                                               float* __restrict__ out) {
    int t = blockIdx.x * 256 + threadIdx.x;
    if (t >= NSAMP * EMB) return;
    int r = t >> 6, d = t & 63;
    int seg = r >> 12, idx = r & (BATCH - 1);
    int node = (seg == 0) ? users[idx] : N_USER + ((seg == 1) ? pos[idx] : neg[idx]);
    float v = (node < N_USER) ? ue[(size_t)node * EMB + d]
                              : ie[(size_t)(node - N_USER) * EMB + d];
    out[(size_t)r * 256 + d] = v;
}

// ---- layers 1,2 output slices: normalized bf16 ego of sampled rows ----
__global__ __launch_bounds__(256) void gather_bf(const int* __restrict__ users,
                                                 const int* __restrict__ pos,
                                                 const int* __restrict__ neg,
                                                 const ushort* __restrict__ ego_bf,
                                                 const float* __restrict__ inv,
                                                 float* __restrict__ out, int col0) {
    int t = blockIdx.x * 256 + threadIdx.x;
    if (t >= NSAMP * EMB) return;
    int r = t >> 6, d = t & 63;
    int seg = r >> 12, idx = r & (BATCH - 1);
    int node = (seg == 0) ? users[idx] : N_USER + ((seg == 1) ? pos[idx] : neg[idx]);
    float v = __uint_as_float(((unsigned int)ego_bf[(size_t)node * 64 + d]) << 16) * inv[node];
    out[(size_t)r * 256 + col0 + d] = v;
}

extern "C" void kernel_launch(void* const* d_in, const int* in_sizes, int n_in,
                              void* d_out, int out_size, void* d_ws, size_t ws_size,
                              hipStream_t stream) {
    const int* users = (const int*)d_in[0];
    const int* pos   = (const int*)d_in[1];
    const int* neg   = (const int*)d_in[2];
    const int* arow  = (const int*)d_in[3];
    const int* acol  = (const int*)d_in[4];
    const float* aval = (const float*)d_in[5];
    const float* ue   = (const float*)d_in[6];
    const float* ie   = (const float*)d_in[7];
    const float* Wgc  = (const float*)d_in[8];
    const float* bgc  = (const float*)d_in[9];
    const float* Wbi  = (const float*)d_in[10];
    const float* bbi  = (const float*)d_in[11];
    float* out = (float*)d_out;

    char* ws = (char*)d_ws;
    size_t o = 0;
    ushort* ego_a   = (ushort*)(ws + o); o += 19200000;
    ushort* ego_b   = (ushort*)(ws + o); o += 19200000;
    ushort* side_cs = (ushort*)(ws + o); o += 38400000;
    int2*   ecv     = (int2*)  (ws + o); o += (size_t)NNZ * 8;   // 19.2 MB
    int2*   tmp_cv  = (int2*)  (ws + o); o += (size_t)NNZ * 8;   // 19.2 MB
    int*    tmp_row = (int*)   (ws + o); o += (size_t)NNZ * 4;   // 9.6 MB
    int*    row_start = (int*) (ws + o); o += 600064;
    float*  inv       = (float*)(ws + o); o += 600064;
    int*    samp      = (int*) (ws + o); o += 49152;
    int*    bcnt      = (int*) (ws + o); o += NB * NR * 4;       // 32 KB
    int*    boff      = (int*) (ws + o); o += NB * NR * 4;
    int*    bcur      = (int*) (ws + o); o += NB * NR * 4;

    // ---- CSR build: two-phase binned (graph reused across all 3 layers) ----
    hipMemsetAsync(bcnt, 0, NB * NR * sizeof(int), stream);
    bin_count<<<NNZ / 256, 256, 0, stream>>>(arow, bcnt);
    scan8k<<<1, 1024, 0, stream>>>(bcnt, boff, bcur);
    bin_scatter<<<NNZ / 256, 256, 0, stream>>>(arow, acol, aval, bcur, tmp_cv, tmp_row);
    csr_from_bins<<<NB, 256, 0, stream>>>(boff, tmp_row, tmp_cv, ecv, row_start);

    // ---- embeddings + layer-0 slice ----
    init_ego_bf<<<(N_NODES * 16 + 255) / 256, 256, 0, stream>>>(
        (const float4*)ue, (const float4*)ie, (uint2*)ego_a);
    gather0<<<(NSAMP * EMB) / 256, 256, 0, stream>>>(users, pos, neg, ue, ie, out);
    build_samp<<<(NSAMP + 255) / 256, 256, 0, stream>>>(users, pos, neg, samp);

    // ---- layer 1: ego_a -> ego_b ----
    spmm_gather<<<N_NODES / 4, 256, 0, stream>>>(row_start, ecv, (const uint4*)ego_a,
                                                 side_cs, nullptr, N_NODES);
    gemm_dense<<<586, 256, 0, stream>>>(side_cs, Wgc, bgc, Wbi, bbi,
                                        ego_b, inv, nullptr, N_NODES, 0, 0, 0);
    gather_bf<<<(NSAMP * EMB) / 256, 256, 0, stream>>>(users, pos, neg, ego_b, inv, out, 64);

    // ---- layer 2: ego_b -> ego_a ----
    spmm_gather<<<N_NODES / 4, 256, 0, stream>>>(row_start, ecv, (const uint4*)ego_b,
                                                 side_cs, nullptr, N_NODES);
    gemm_dense<<<586, 256, 0, stream>>>(side_cs, Wgc, bgc, Wbi, bbi,
                                        ego_a, inv, nullptr, N_NODES, 1, 0, 0);
    gather_bf<<<(NSAMP * EMB) / 256, 256, 0, stream>>>(users, pos, neg, ego_a, inv, out, 128);

    // ---- layer 3: sampled rows only, straight into out ----
    spmm_gather<<<NSAMP / 4, 256, 0, stream>>>(row_start, ecv, (const uint4*)ego_a,
                                               side_cs, samp, NSAMP);
    gemm_dense<<<48, 256, 0, stream>>>(side_cs, Wgc, bgc, Wbi, bbi,
                                       nullptr, nullptr, out, NSAMP, 2, 1, 192);
}

// Round 9
// 431.285 us; speedup vs baseline: 2.7273x; 1.2464x over previous
//
#include <hip/hip_runtime.h>

typedef short bf16x8 __attribute__((ext_vector_type(8)));
typedef float f32x4  __attribute__((ext_vector_type(4)));

#define N_USER 50000
#define N_ITEM 100000
#define N_NODES 150000
#define EMB 64
#define NNZ 2400000
#define BATCH 4096
#define NSAMP (3 * BATCH)     // 12288 sampled rows
#define NB 256                // row-range buckets
#define RPB 587               // rows per bucket (256*587 = 150272 >= 150001)
#define BS_GRID 256           // binning blocks
#define EPB (NNZ / BS_GRID)   // 9375 edges per block

// bf16 round-to-nearest-even; low 16 bits hold the bf16
__device__ __forceinline__ unsigned int bf16_rne(float x) {
    unsigned int u = __float_as_uint(x);
    return (u + 0x7fffu + ((u >> 16) & 1u)) >> 16;
}
__device__ __forceinline__ float bflo(unsigned int u) { return __uint_as_float(u << 16); }
__device__ __forceinline__ float bfhi(unsigned int u) { return __uint_as_float(u & 0xffff0000u); }

__device__ __forceinline__ void fma8(float v, const uint4& x, float* acc) {
    acc[0] = fmaf(v, bflo(x.x), acc[0]); acc[1] = fmaf(v, bfhi(x.x), acc[1]);
    acc[2] = fmaf(v, bflo(x.y), acc[2]); acc[3] = fmaf(v, bfhi(x.y), acc[3]);
    acc[4] = fmaf(v, bflo(x.z), acc[4]); acc[5] = fmaf(v, bfhi(x.z), acc[5]);
    acc[6] = fmaf(v, bflo(x.w), acc[6]); acc[7] = fmaf(v, bfhi(x.w), acc[7]);
}
__device__ __forceinline__ uint4 pack8(const float* f) {
    return make_uint4((bf16_rne(f[1]) << 16) | bf16_rne(f[0]),
                      (bf16_rne(f[3]) << 16) | bf16_rne(f[2]),
                      (bf16_rne(f[5]) << 16) | bf16_rne(f[4]),
                      (bf16_rne(f[7]) << 16) | bf16_rne(f[6]));
}

// ---------------- init: ego_bf = bf16(concat(user_emb, item_emb)) ----------------
__global__ __launch_bounds__(256) void init_ego_bf(const float4* __restrict__ ue,
                                                   const float4* __restrict__ ie,
                                                   uint2* __restrict__ ego_bf) {
    int i = blockIdx.x * 256 + threadIdx.x;            // over N_NODES*16 float4
    if (i >= N_NODES * 16) return;
    const int NU4 = N_USER * 16;
    float4 v = (i < NU4) ? ue[i] : ie[i - NU4];
    ego_bf[i] = make_uint2((bf16_rne(v.y) << 16) | bf16_rne(v.x),
                           (bf16_rne(v.w) << 16) | bf16_rne(v.z));
}

// ================= CSR build: deterministic binned, per-block dense sub-regions =================
// A1: per-block LDS histogram over 256 buckets -> cnt[bucket*BS_GRID + block] (no global atomics)
__global__ __launch_bounds__(256) void bin_count(const int* __restrict__ rows,
                                                 int* __restrict__ cnt) {
    __shared__ int h[NB];
    const int t = threadIdx.x, blk = blockIdx.x;
    h[t] = 0;
    __syncthreads();
    const int e0 = blk * EPB;
    for (int i = t; i < EPB; i += 256) atomicAdd(&h[rows[e0 + i] / RPB], 1);
    __syncthreads();
    cnt[t * BS_GRID + blk] = h[t];
}

// A2: in-place exclusive scan of cnt[65536] (bucket-major, then block) -> base[]
__global__ __launch_bounds__(1024) void scan64k(int* __restrict__ cnt) {
    __shared__ int s[1024];
    const int t = threadIdx.x;
    int loc[64], sum = 0;
#pragma unroll
    for (int i = 0; i < 64; ++i) { loc[i] = cnt[t * 64 + i]; sum += loc[i]; }
    s[t] = sum;
    for (int off = 1; off < 1024; off <<= 1) {
        __syncthreads();
        int add = (t >= off) ? s[t - off] : 0;
        __syncthreads();
        s[t] += add;
    }
    __syncthreads();
    int run = s[t] - sum;
#pragma unroll
    for (int i = 0; i < 64; ++i) { cnt[t * 64 + i] = run; run += loc[i]; }
}

// A3: re-read chunk, pack (col, val|row10) 8B records into this block's dense sub-regions.
// 10 low mantissa bits of val carry row-in-bucket (rel err ~1.2e-4, << bf16 rounding).
__global__ __launch_bounds__(256) void bin_scatter(const int* __restrict__ rows,
                                                   const int* __restrict__ cols,
                                                   const float* __restrict__ vals,
                                                   const int* __restrict__ base,
                                                   int2* __restrict__ tmp_cv) {
    __shared__ int gbase[NB];
    __shared__ int cur[NB];
    const int t = threadIdx.x, blk = blockIdx.x;
    gbase[t] = base[t * BS_GRID + blk];
    cur[t] = 0;
    __syncthreads();
    const int e0 = blk * EPB;
    for (int i = t; i < EPB; i += 256) {
        int e = e0 + i;
        int r = rows[e];
        int b = r / RPB;
        int slot = atomicAdd(&cur[b], 1);
        unsigned vv = (__float_as_uint(vals[e]) & ~1023u) | (unsigned)(r - b * RPB);
        tmp_cv[gbase[b] + slot] = make_int2(cols[e], (int)vv);
    }
}

// B: one block per bucket — LDS row histogram + scan gives row_start AND CSR scatter
// within a ~75 KB L2-resident window. Bucket record base == CSR base.
__global__ __launch_bounds__(256) void csr_from_bins(const int* __restrict__ base,
                                                     const int2* __restrict__ tmp_cv,
                                                     int2* __restrict__ ecv,
                                                     int* __restrict__ row_start) {
    __shared__ int rcnt[RPB];
    __shared__ int excl[RPB + 1];
    __shared__ int sc[256];
    const int b = blockIdx.x;
    const int row0 = b * RPB;
    const int t = threadIdx.x;
    const int beg = base[b * BS_GRID];
    const int end = (b == NB - 1) ? NNZ : base[(b + 1) * BS_GRID];

    for (int i = t; i < RPB; i += 256) rcnt[i] = 0;
    __syncthreads();
    for (int i = beg + t; i < end; i += 256) atomicAdd(&rcnt[tmp_cv[i].y & 1023], 1);
    __syncthreads();

    // exclusive scan over 587: 3 values per thread + 256-scan of partial sums
    const int i0 = t * 3, i1 = i0 + 1, i2 = i0 + 2;
    int v0 = (i0 < RPB) ? rcnt[i0] : 0;
    int v1 = (i1 < RPB) ? rcnt[i1] : 0;
    int v2 = (i2 < RPB) ? rcnt[i2] : 0;
    int sum = v0 + v1 + v2;
    sc[t] = sum;
    for (int off = 1; off < 256; off <<= 1) {
        __syncthreads();
        int add = (t >= off) ? sc[t - off] : 0;
        __syncthreads();
        sc[t] += add;
    }
    __syncthreads();
    int ex = sc[t] - sum;
    if (i0 <= RPB) excl[i0] = ex;
    if (i1 <= RPB) excl[i1] = ex + v0;
    if (i2 <= RPB) excl[i2] = ex + v0 + v1;
    __syncthreads();

    int lim = N_NODES + 1 - row0;                      // include global sentinel row
    if (lim > RPB) lim = RPB;                          // next bucket provides row_start[row0+RPB]
    for (int i = t; i < lim; i += 256) row_start[row0 + i] = beg + excl[i];
    __syncthreads();
    for (int i = t; i < RPB; i += 256) rcnt[i] = excl[i];   // cursors
    __syncthreads();
    for (int i = beg + t; i < end; i += 256) {
        int2 rec = tmp_cv[i];
        int r10 = rec.y & 1023;
        int dst = beg + atomicAdd(&rcnt[r10], 1);
        ecv[dst] = make_int2(rec.x, rec.y & ~1023);    // cleaned val
    }
}

// ---- sampled node list ----
__global__ __launch_bounds__(256) void build_samp(const int* __restrict__ users,
                                                  const int* __restrict__ pos,
                                                  const int* __restrict__ neg,
                                                  int* __restrict__ samp) {
    int t = blockIdx.x * 256 + threadIdx.x;
    if (t >= NSAMP) return;
    int seg = t >> 12, idx = t & (BATCH - 1);
    samp[t] = (seg == 0) ? users[idx] : N_USER + ((seg == 1) ? pos[idx] : neg[idx]);
}

// ======== kernel 1: CSR gather-reduce (bf16 ego) -> side_cs[r] = [side(64) | ego*side(64)] bf16 ====
__global__ __launch_bounds__(256) void spmm_gather(const int* __restrict__ row_start,
                                                   const int2* __restrict__ ecv,
                                                   const uint4* __restrict__ ego_bf, // 8 uint4/row
                                                   ushort* __restrict__ side_cs,    // n_rows x 128 bf16
                                                   const int* __restrict__ node_list,
                                                   int n_rows) {
    const int t = threadIdx.x;
    const int lane = t & 63;
    const int r = blockIdx.x * 4 + (t >> 6);
    if (r >= n_rows) return;
    const int node = node_list ? node_list[r] : r;
    const int j8 = lane >> 3;
    const int g8 = lane & 7;

    const int s0 = row_start[node];
    const int s1 = row_start[node + 1];
    const uint4 selfv = ego_bf[(size_t)node * 8 + g8];

    float acc[8] = {0.f, 0.f, 0.f, 0.f, 0.f, 0.f, 0.f, 0.f};
    for (int e0 = s0; e0 < s1; e0 += 64) {
        const int cnt = min(64, s1 - e0);
        int2 m = make_int2(0, 0);                      // zero-fill: pad slots are no-ops
        if (lane < cnt) m = ecv[e0 + lane];
        for (int jj = 0; jj < cnt; jj += 16) {         // 16 edges per iter (2 x 8-wide loads)
            int   i0 = jj + j8;
            int   c0 = __shfl(m.x, i0);
            float v0 = __int_as_float(__shfl(m.y, i0));
            const uint4 x0 = ego_bf[(size_t)c0 * 8 + g8];
            int   i1 = jj + 8 + j8;
            int   c1 = __shfl(m.x, i1);
            float v1 = __int_as_float(__shfl(m.y, i1));
            const uint4 x1 = ego_bf[(size_t)c1 * 8 + g8];
            fma8(v0, x0, acc);
            fma8(v1, x1, acc);
        }
    }
#pragma unroll
    for (int c = 0; c < 8; ++c) {
        acc[c] += __shfl_xor(acc[c], 8);
        acc[c] += __shfl_xor(acc[c], 16);
        acc[c] += __shfl_xor(acc[c], 32);
    }
    uint4* scs4 = (uint4*)side_cs;                     // row = 16 uint4 (256 B)
    if (j8 == 0) {
        scs4[(size_t)r * 16 + g8] = pack8(acc);        // side half
    } else if (j8 == 1) {
        float cs[8] = { bflo(selfv.x) * acc[0], bfhi(selfv.x) * acc[1],
                        bflo(selfv.y) * acc[2], bfhi(selfv.y) * acc[3],
                        bflo(selfv.z) * acc[4], bfhi(selfv.z) * acc[5],
                        bflo(selfv.w) * acc[6], bfhi(selfv.w) * acc[7] };
        scs4[(size_t)r * 16 + 8 + g8] = pack8(cs);     // ego*side half
    }
}

// ======== kernel 2: MFMA GEMM [n_rows x 128]_bf16 @ [128 x 64] + bias + leaky + row-norm ========
#define WROW 136   // padded LDS row (bf16 elems): 272 B -> bank stride 4
__global__ __launch_bounds__(256) void gemm_dense(const ushort* __restrict__ side_cs,
                                                  const float* __restrict__ Wgc,
                                                  const float* __restrict__ bgc,
                                                  const float* __restrict__ Wbi,
                                                  const float* __restrict__ bbi,
                                                  ushort* __restrict__ ego_out,
                                                  float* __restrict__ inv_norm,
                                                  float* __restrict__ out,
                                                  int n_rows, int layer, int out_mode, int col0) {
    __shared__ ushort wT[64 * WROW];                   // wT[n][k] = Wstack[k][n], bf16
    const int t = threadIdx.x;
    const float* Wg = Wgc + layer * 4096;
    const float* Wb = Wbi + layer * 4096;
    for (int idx = t; idx < 8192; idx += 256) {
        int n = idx >> 7, k = idx & 127;
        float w = (k < 64) ? Wg[k * 64 + n] : Wb[(k - 64) * 64 + n];
        wT[n * WROW + k] = (ushort)bf16_rne(w);
    }
    __syncthreads();

    const int lane = t & 63;
    const int wv = t >> 6;
    const int l15 = lane & 15, quad = lane >> 4;

    const bf16x8* wt8 = (const bf16x8*)wT;             // row stride WROW/8 = 17
    bf16x8 bfr[4][4];
#pragma unroll
    for (int ks = 0; ks < 4; ++ks)
#pragma unroll
        for (int nt = 0; nt < 4; ++nt)
            bfr[ks][nt] = wt8[(nt * 16 + l15) * 17 + ks * 4 + quad];

    float bias[4];
#pragma unroll
    for (int nt = 0; nt < 4; ++nt) {
        int ccol = nt * 16 + l15;
        bias[nt] = bgc[layer * 64 + ccol] + bbi[layer * 64 + ccol];
    }

    const bf16x8* sc8 = (const bf16x8*)side_cs;        // row stride 16

    for (int i = 0; i < 4; ++i) {
        int tile = (blockIdx.x * 4 + wv) * 4 + i;
        int n0 = tile * 16;
        if (n0 >= n_rows) break;
        int mrow = n0 + l15;
        if (mrow >= n_rows) mrow = n_rows - 1;         // clamp; masked at store

        f32x4 acc[4] = {{0,0,0,0}, {0,0,0,0}, {0,0,0,0}, {0,0,0,0}};
#pragma unroll
        for (int ks = 0; ks < 4; ++ks) {
            bf16x8 afr = sc8[(size_t)mrow * 16 + ks * 4 + quad];  // A[m=lane&15][k=quad*8+j]
#pragma unroll
            for (int nt = 0; nt < 4; ++nt)
                acc[nt] = __builtin_amdgcn_mfma_f32_16x16x32_bf16(afr, bfr[ks][nt], acc[nt], 0, 0, 0);
        }

        float x[4][4];
        float ss[4] = {0.f, 0.f, 0.f, 0.f};
#pragma unroll
        for (int nt = 0; nt < 4; ++nt)
#pragma unroll
            for (int rg = 0; rg < 4; ++rg) {
                float v = acc[nt][rg] + bias[nt];
                v = (v >= 0.f) ? v : 0.2f * v;
                x[nt][rg] = v;
                ss[rg] = fmaf(v, v, ss[rg]);
            }
#pragma unroll
        for (int rg = 0; rg < 4; ++rg) {
            ss[rg] += __shfl_xor(ss[rg], 1);
            ss[rg] += __shfl_xor(ss[rg], 2);
            ss[rg] += __shfl_xor(ss[rg], 4);
            ss[rg] += __shfl_xor(ss[rg], 8);
        }
#pragma unroll
        for (int rg = 0; rg < 4; ++rg) {
            int row = n0 + quad * 4 + rg;
            if (row >= n_rows) continue;
            float invr = 1.0f / fmaxf(sqrtf(ss[rg]), 1e-12f);
            if (out_mode) {
#pragma unroll
                for (int nt = 0; nt < 4; ++nt)
                    out[(size_t)row * 256 + col0 + nt * 16 + l15] = x[nt][rg] * invr;
            } else {
#pragma unroll
                for (int nt = 0; nt < 4; ++nt)
                    ego_out[(size_t)row * 64 + nt * 16 + l15] = (ushort)bf16_rne(x[nt][rg]);
                if (l15 == 0) inv_norm[row] = invr;
            }
        }
    }
}

// ---- layer-0 output slice: raw fp32 embeddings of sampled rows ----
__global__ __launch_bounds__(256) void gather0(const int* __restrict__ users,
                                               const int* __restrict__ pos,
                                               const int* __restrict__ neg,
                                               const float* __restrict__ ue,
                                               const float* __restrict__ ie,
                                               float* __restrict__ out) {
    int t = blockIdx.x * 256 + threadIdx.x;
    if (t >= NSAMP * EMB) return;
    int r = t >> 6, d = t & 63;
    int seg = r >> 12, idx = r & (BATCH - 1);
    int node = (seg == 0) ? users[idx] : N_USER + ((seg == 1) ? pos[idx] : neg[idx]);
    float v = (node < N_USER) ? ue[(size_t)node * EMB + d]
                              : ie[(size_t)(node - N_USER) * EMB + d];
    out[(size_t)r * 256 + d] = v;
}

// ---- layers 1,2 output slices: normalized bf16 ego of sampled rows ----
__global__ __launch_bounds__(256) void gather_bf(const int* __restrict__ users,
                                                 const int* __restrict__ pos,
                                                 const int* __restrict__ neg,
                                                 const ushort* __restrict__ ego_bf,
                                                 const float* __restrict__ inv,
                                                 float* __restrict__ out, int col0) {
    int t = blockIdx.x * 256 + threadIdx.x;
    if (t >= NSAMP * EMB) return;
    int r = t >> 6, d = t & 63;
    int seg = r >> 12, idx = r & (BATCH - 1);
    int node = (seg == 0) ? users[idx] : N_USER + ((seg == 1) ? pos[idx] : neg[idx]);
    float v = __uint_as_float(((unsigned int)ego_bf[(size_t)node * 64 + d]) << 16) * inv[node];
    out[(size_t)r * 256 + col0 + d] = v;
}

extern "C" void kernel_launch(void* const* d_in, const int* in_sizes, int n_in,
                              void* d_out, int out_size, void* d_ws, size_t ws_size,
                              hipStream_t stream) {
    const int* users = (const int*)d_in[0];
    const int* pos   = (const int*)d_in[1];
    const int* neg   = (const int*)d_in[2];
    const int* arow  = (const int*)d_in[3];
    const int* acol  = (const int*)d_in[4];
    const float* aval = (const float*)d_in[5];
    const float* ue   = (const float*)d_in[6];
    const float* ie   = (const float*)d_in[7];
    const float* Wgc  = (const float*)d_in[8];
    const float* bgc  = (const float*)d_in[9];
    const float* Wbi  = (const float*)d_in[10];
    const float* bbi  = (const float*)d_in[11];
    float* out = (float*)d_out;

    char* ws = (char*)d_ws;
    size_t o = 0;
    ushort* ego_a   = (ushort*)(ws + o); o += 19200000;
    ushort* ego_b   = (ushort*)(ws + o); o += 19200000;
    ushort* side_cs = (ushort*)(ws + o); o += 38400000;
    int2*   ecv     = (int2*)  (ws + o); o += (size_t)NNZ * 8;   // 19.2 MB
    int2*   tmp_cv  = (int2*)  (ws + o); o += (size_t)NNZ * 8;   // 19.2 MB
    int*    cnt     = (int*)   (ws + o); o += NB * BS_GRID * 4;  // 256 KB
    int*    row_start = (int*) (ws + o); o += 600064;
    float*  inv       = (float*)(ws + o); o += 600064;
    int*    samp      = (int*) (ws + o); o += 49152;

    // ---- CSR build: deterministic binned (graph reused across all 3 layers) ----
    bin_count<<<BS_GRID, 256, 0, stream>>>(arow, cnt);
    scan64k<<<1, 1024, 0, stream>>>(cnt);
    bin_scatter<<<BS_GRID, 256, 0, stream>>>(arow, acol, aval, cnt, tmp_cv);
    csr_from_bins<<<NB, 256, 0, stream>>>(cnt, tmp_cv, ecv, row_start);

    // ---- embeddings + layer-0 slice ----
    init_ego_bf<<<(N_NODES * 16 + 255) / 256, 256, 0, stream>>>(
        (const float4*)ue, (const float4*)ie, (uint2*)ego_a);
    gather0<<<(NSAMP * EMB) / 256, 256, 0, stream>>>(users, pos, neg, ue, ie, out);
    build_samp<<<(NSAMP + 255) / 256, 256, 0, stream>>>(users, pos, neg, samp);

    // ---- layer 1: ego_a -> ego_b ----
    spmm_gather<<<N_NODES / 4, 256, 0, stream>>>(row_start, ecv, (const uint4*)ego_a,
                                                 side_cs, nullptr, N_NODES);
    gemm_dense<<<586, 256, 0, stream>>>(side_cs, Wgc, bgc, Wbi, bbi,
                                        ego_b, inv, nullptr, N_NODES, 0, 0, 0);
    gather_bf<<<(NSAMP * EMB) / 256, 256, 0, stream>>>(users, pos, neg, ego_b, inv, out, 64);

    // ---- layer 2: ego_b -> ego_a ----
    spmm_gather<<<N_NODES / 4, 256, 0, stream>>>(row_start, ecv, (const uint4*)ego_b,
                                                 side_cs, nullptr, N_NODES);
    gemm_dense<<<586, 256, 0, stream>>>(side_cs, Wgc, bgc, Wbi, bbi,
                                        ego_a, inv, nullptr, N_NODES, 1, 0, 0);
    gather_bf<<<(NSAMP * EMB) / 256, 256, 0, stream>>>(users, pos, neg, ego_a, inv, out, 128);

    // ---- layer 3: sampled rows only, straight into out ----
    spmm_gather<<<NSAMP / 4, 256, 0, stream>>>(row_start, ecv, (const uint4*)ego_a,
                                               side_cs, samp, NSAMP);
    gemm_dense<<<48, 256, 0, stream>>>(side_cs, Wgc, bgc, Wbi, bbi,
                                       nullptr, nullptr, out, NSAMP, 2, 1, 192);
}